// Round 10
// baseline (211.390 us; speedup 1.0000x reference)
//
#include <hip/hip_runtime.h>

typedef unsigned short u16;
typedef unsigned int u32;
typedef __attribute__((ext_vector_type(8))) short bf16x8;
typedef __attribute__((ext_vector_type(4))) float f32x4;
typedef __attribute__((ext_vector_type(4))) u32 u32x4;

#define T_TOK 3072
#define HID 2048
#define NH 16
#define NKV 4
#define HD 128
#define QKVN 3072
#define ATT_SCALE 0.08838834764831845f
#define LOG2E 1.4426950408889634f
#define SCL2 (ATT_SCALE * LOG2E)

__device__ __forceinline__ u16 f2bf(float x) {
  u32 u = __builtin_bit_cast(u32, x);
  u = u + 0x7FFFu + ((u >> 16) & 1u);
  return (u16)(u >> 16);
}
__device__ __forceinline__ float bf2f(u16 h) {
  return __builtin_bit_cast(float, (u32)h << 16);
}
__device__ __forceinline__ void gload16(const void* g, void* l) {
  __builtin_amdgcn_global_load_lds((const __attribute__((address_space(1))) void*)g,
                                   (__attribute__((address_space(3))) void*)l, 16, 0, 0);
}

// ---------------- fp32 -> bf16 convert ----------------
__global__ void k_cvt(const float* __restrict__ src, u16* __restrict__ dst, int n) {
  int i = (blockIdx.x * 256 + threadIdx.x) * 4;
  int stride = gridDim.x * 256 * 4;
  for (; i < n; i += stride) {
    float4 v = *(const float4*)(src + i);
    u32 lo = (u32)f2bf(v.x) | ((u32)f2bf(v.y) << 16);
    u32 hi = (u32)f2bf(v.z) | ((u32)f2bf(v.w) << 16);
    *(uint2*)(dst + i) = make_uint2(lo, hi);
  }
}

// ---------------- 2-phase double-buffered GEMM: C = A * B^T ----------------
// (unchanged — matched prediction in round 7)
template <int MR, int NR, bool OUT_BF16, bool VT_MODE>
__global__ __launch_bounds__(512) void k_gemm2p(const u16* __restrict__ A,
                                                const u16* __restrict__ B,
                                                void* __restrict__ Cp,
                                                u16* __restrict__ vt,
                                                int M, int N, int K) {
  constexpr int BM = 32 * MR;
  constexpr int BN = 64 * NR;
  __shared__ u16 Ash[2][BM * 64];
  __shared__ u16 Bsh[2][BN * 64];
  const int tid = threadIdx.x;
  const int wv = tid >> 6, ln = tid & 63;
  const int wr = wv >> 2, wc = wv & 3;
  const int g = ln >> 4, r16 = ln & 15;
  const int m0 = blockIdx.y * BM, n0 = blockIdx.x * BN;
  const int NT = K >> 6;
  const int srow = ln >> 3;                   // row within 8-row DMA block
  const int sswz = ((ln & 7) ^ srow) << 3;    // pre-swizzled source col (elems)
  const u16* Abase = A + (size_t)m0 * K;
  const u16* Bbase = B + (size_t)n0 * K;
  const int xorc = (r16 & 7) << 3;

  f32x4 acc[MR][NR] = {};

  auto stage = [&](int buf, int T) {
#pragma unroll
    for (int a = 0; a < BM / 64; ++a)
      gload16(Abase + (size_t)(a * 64 + wv * 8 + srow) * K + T * 64 + sswz,
              &Ash[buf][(a * 64 + wv * 8) * 64]);
#pragma unroll
    for (int b = 0; b < BN / 64; ++b)
      gload16(Bbase + (size_t)(b * 64 + wv * 8 + srow) * K + T * 64 + sswz,
              &Bsh[buf][(b * 64 + wv * 8) * 64]);
  };

  stage(0, 0);
  __syncthreads();
  int cur = 0;
  for (int T = 0; T < NT; ++T) {
    if (T + 1 < NT) stage(cur ^ 1, T + 1);
    const u16* As = Ash[cur];
    const u16* Bs = Bsh[cur];
#pragma unroll
    for (int kk = 0; kk < 2; ++kk) {
      const int ecol = (kk * 32 + g * 8) ^ xorc;
      bf16x8 af[MR], bfr[NR];
#pragma unroll
      for (int m = 0; m < MR; ++m)
        af[m] = *(const bf16x8*)&As[(wr * (MR * 16) + m * 16 + r16) * 64 + ecol];
#pragma unroll
      for (int n = 0; n < NR; ++n)
        bfr[n] = *(const bf16x8*)&Bs[(wc * (NR * 16) + n * 16 + r16) * 64 + ecol];
      __builtin_amdgcn_s_setprio(1);
#pragma unroll
      for (int m = 0; m < MR; ++m)
#pragma unroll
        for (int n = 0; n < NR; ++n)
          acc[m][n] = __builtin_amdgcn_mfma_f32_16x16x32_bf16(af[m], bfr[n], acc[m][n], 0, 0, 0);
      __builtin_amdgcn_s_setprio(0);
    }
    __syncthreads();
    cur ^= 1;
  }
  // ---- epilogue ----
#pragma unroll
  for (int n = 0; n < NR; ++n) {
    int col = n0 + wc * (NR * 16) + n * 16 + r16;
    bool tov = VT_MODE && (col >= 2560);
#pragma unroll
    for (int m = 0; m < MR; ++m) {
      int row = m0 + wr * (MR * 16) + m * 16 + g * 4;
      if (tov) {
        u32 lo2 = (u32)f2bf(acc[m][n][0]) | ((u32)f2bf(acc[m][n][1]) << 16);
        u32 hi2 = (u32)f2bf(acc[m][n][2]) | ((u32)f2bf(acc[m][n][3]) << 16);
        *(uint2*)&vt[(size_t)(col - 2560) * T_TOK + row] = make_uint2(lo2, hi2);
      } else {
#pragma unroll
        for (int j = 0; j < 4; ++j) {
          if (OUT_BF16)
            ((u16*)Cp)[(size_t)(row + j) * N + col] = f2bf(acc[m][n][j]);
          else
            ((float*)Cp)[(size_t)(row + j) * N + col] = acc[m][n][j];
        }
      }
    }
  }
}

// ---------------- RMSNorm + RoPE (in-place on bf16 qkv, Q and K only) ----------------
__global__ void k_normrope(u16* __restrict__ qkv, const float* __restrict__ cs,
                           const float* __restrict__ sn, const float* __restrict__ qw,
                           const float* __restrict__ kw) {
  int t = blockIdx.x;
  int idx = blockIdx.y * 4 + (threadIdx.x >> 6);  // 0..19
  int l = threadIdx.x & 63;
  bool isq = idx < NH;
  int off = isq ? idx * HD : HID + (idx - NH) * HD;
  u16* p = qkv + (size_t)t * QKVN + off;
  float x0 = bf2f(p[l]), x1 = bf2f(p[l + 64]);
  float ss = x0 * x0 + x1 * x1;
#pragma unroll
  for (int d = 1; d < 64; d <<= 1) ss += __shfl_xor(ss, d, 64);
  float rs = rsqrtf(ss * (1.0f / 128.0f) + 1e-6f);
  const float* w = isq ? qw : kw;
  float xn0 = x0 * rs * w[l];
  float xn1 = x1 * rs * w[l + 64];
  const float* ct = cs + (size_t)t * HD;
  const float* st = sn + (size_t)t * HD;
  float o0 = xn0 * ct[l] - xn1 * st[l];
  float o1 = xn1 * ct[l + 64] + xn0 * st[l + 64];
  p[l] = f2bf(o0);
  p[l + 64] = f2bf(o1);
}

// ---------------- GQA attention: swapped-QK in-register softmax ----------------
// mfma(K,Q) puts P-row t=r16 lane-local: row-max = in-reg chain + 2 shfl;
// l-sum deferred to epilogue; P never touches LDS (pack + 16 bpermute ->
// PV A-fragments). Mask only on last tile (s0 > t0-60) and window tile.
// T14 reg-staging kept. LDS 32KB (Plds deleted).
__global__ __launch_bounds__(256, 4) void k_attn(const u16* __restrict__ qkv,
                                                 const u16* __restrict__ vt,
                                                 u16* __restrict__ attn) {
  __shared__ u16 Ksh[64 * 128];     // [s][granule ^ (s&7)]
  __shared__ u16 Vsh[128 * 64];     // [d][granule ^ (d&7)]
  const int id = blockIdx.x;
  const int xcd = id & 7, slot = id >> 3;              // slot 0..95
  const int hkv = xcd >> 1;                            // 2 XCDs per kv-group
  const int t0 = (191 - (slot * 2 + (xcd & 1))) * 16;  // reversed: long blocks first
  const int tid = threadIdx.x, wv = tid >> 6, ln = tid & 63;
  const int g = ln >> 4, r16 = ln & 15;
  const int h = hkv * 4 + wv;
  const int swz = r16 & 7;
  const bool ghi = (g >> 1) != 0;
  const int L0 = r16 + 16 * ((2 * g) & 3);   // src lane for P blocks B0
  const int L1 = r16 + 16 * ((2 * g + 1) & 3);

  bf16x8 qf[4];
  const u16* qrow = qkv + (size_t)(t0 + r16) * QKVN + h * HD;
#pragma unroll
  for (int kk = 0; kk < 4; ++kk) qf[kk] = *(const bf16x8*)(qrow + kk * 32 + g * 8);

  float m_run = -1e30f, l_part = 0.f;   // row t = t0 + r16 (per-lane)
  f32x4 acc_o[8] = {};                  // rows t = t0 + g*4+j, cols d = db*16+r16

  const u16* Kbase = qkv + HID + hkv * HD;
  const u16* Vbase = vt + (size_t)(hkv * HD) * T_TOK;

  int lo = t0 - 1023;
  if (lo < 0) lo = 0;
  lo &= ~63;
  const int t_hi = t0 + 15;

  // per-thread staging coordinates (4 chunks of 256 threads)
  int ksr[4], kcc[4], vdr[4], vcc[4];
#pragma unroll
  for (int ph = 0; ph < 4; ++ph) {
    int q = ph * 256 + tid;
    ksr[ph] = q >> 4; kcc[ph] = q & 15;
    vdr[ph] = q >> 3; vcc[ph] = q & 7;
  }

  // ---- prologue: stage first tile ----
#pragma unroll
  for (int ph = 0; ph < 4; ++ph) {
    *(bf16x8*)&Ksh[ksr[ph] * 128 + ((kcc[ph] ^ (ksr[ph] & 7)) << 3)] =
        *(const bf16x8*)(Kbase + (size_t)(lo + ksr[ph]) * QKVN + (kcc[ph] << 3));
    *(bf16x8*)&Vsh[vdr[ph] * 64 + ((vcc[ph] ^ (vdr[ph] & 7)) << 3)] =
        *(const bf16x8*)(Vbase + (size_t)vdr[ph] * T_TOK + lo + (vcc[ph] << 3));
  }
  __syncthreads();

  for (int s0 = lo; s0 <= t_hi; s0 += 64) {
    // ---- T14: issue next tile's global loads (held in regs) ----
    const bool has_next = (s0 + 64) <= t_hi;
    bf16x8 kst[4], vst[4];
    if (has_next) {
      const int sn0 = s0 + 64;
#pragma unroll
      for (int ph = 0; ph < 4; ++ph) {
        kst[ph] = *(const bf16x8*)(Kbase + (size_t)(sn0 + ksr[ph]) * QKVN + (kcc[ph] << 3));
        vst[ph] = *(const bf16x8*)(Vbase + (size_t)vdr[ph] * T_TOK + sn0 + (vcc[ph] << 3));
      }
    }

    // ---- S^T = K Q^T (swapped): sc[sb] rows s_local=g*4+j, cols t=r16 ----
    f32x4 sc[4] = {};
    __builtin_amdgcn_s_setprio(1);
#pragma unroll
    for (int sb = 0; sb < 4; ++sb) {
#pragma unroll
      for (int kk = 0; kk < 4; ++kk) {
        const bf16x8 kf =
            *(const bf16x8*)&Ksh[(sb * 16 + r16) * 128 + (((kk * 4 + g) ^ swz) << 3)];
        sc[sb] = __builtin_amdgcn_mfma_f32_16x16x32_bf16(kf, qf[kk], sc[sb], 0, 0, 0);
      }
    }
    __builtin_amdgcn_s_setprio(0);

    // ---- mask (specialized) + row max ----
    const bool mtile = (s0 > t0 - 60) || (t0 >= 1024 && s0 == lo);
    const int t = t0 + r16;
    float pmax = -__builtin_inff();
    if (mtile) {
#pragma unroll
      for (int sb = 0; sb < 4; ++sb)
#pragma unroll
        for (int j = 0; j < 4; ++j) {
          int s = s0 + sb * 16 + g * 4 + j;
          bool ok = (s <= (t | 3)) && (t - s < 1024);
          float x = ok ? sc[sb][j] : -__builtin_inff();
          sc[sb][j] = x;
          pmax = fmaxf(pmax, x);
        }
    } else {
#pragma unroll
      for (int sb = 0; sb < 4; ++sb)
#pragma unroll
        for (int j = 0; j < 4; ++j) pmax = fmaxf(pmax, sc[sb][j]);
    }
    pmax = fmaxf(pmax, __shfl_xor(pmax, 16, 64));
    pmax = fmaxf(pmax, __shfl_xor(pmax, 32, 64));

    // ---- defer-max online softmax (log2 domain) ----
    float needv = fmaf(pmax, SCL2, -m_run);
    if (!__all(needv <= 11.5f)) {
      float mnew = fmaxf(m_run, pmax * SCL2);
      float fac = exp2f(m_run - mnew);
      m_run = mnew;
      l_part *= fac;
      float fj[4];
#pragma unroll
      for (int j = 0; j < 4; ++j) fj[j] = __shfl(fac, (ln & 48) + g * 4 + j, 64);
#pragma unroll
      for (int db = 0; db < 8; ++db)
#pragma unroll
        for (int j = 0; j < 4; ++j) acc_o[db][j] *= fj[j];
    }
    const float nm = -m_run;
    u32 w0[4], w1[4];
#pragma unroll
    for (int sb = 0; sb < 4; ++sb) {
      float e0 = exp2f(fmaf(sc[sb][0], SCL2, nm));
      float e1 = exp2f(fmaf(sc[sb][1], SCL2, nm));
      float e2 = exp2f(fmaf(sc[sb][2], SCL2, nm));
      float e3 = exp2f(fmaf(sc[sb][3], SCL2, nm));
      l_part += (e0 + e1) + (e2 + e3);
      w0[sb] = (u32)f2bf(e0) | ((u32)f2bf(e1) << 16);
      w1[sb] = (u32)f2bf(e2) | ((u32)f2bf(e3) << 16);
    }

    // ---- O += P V: P rearranged lane->A-fragment via shfl (no LDS) ----
    __builtin_amdgcn_s_setprio(1);
#pragma unroll
    for (int s32 = 0; s32 < 2; ++s32) {
      u32 a0 = __shfl(w0[2 * s32], L0, 64), b0 = __shfl(w0[2 * s32 + 1], L0, 64);
      u32 a1 = __shfl(w1[2 * s32], L0, 64), b1 = __shfl(w1[2 * s32 + 1], L0, 64);
      u32 a2 = __shfl(w0[2 * s32], L1, 64), b2 = __shfl(w0[2 * s32 + 1], L1, 64);
      u32 a3 = __shfl(w1[2 * s32], L1, 64), b3 = __shfl(w1[2 * s32 + 1], L1, 64);
      u32x4 pw;
      pw[0] = ghi ? b0 : a0;
      pw[1] = ghi ? b1 : a1;
      pw[2] = ghi ? b2 : a2;
      pw[3] = ghi ? b3 : a3;
      const bf16x8 pa = __builtin_bit_cast(bf16x8, pw);
#pragma unroll
      for (int db = 0; db < 8; ++db) {
        const bf16x8 vb =
            *(const bf16x8*)&Vsh[(db * 16 + r16) * 64 + (((s32 * 4 + g) ^ swz) << 3)];
        acc_o[db] = __builtin_amdgcn_mfma_f32_16x16x32_bf16(pa, vb, acc_o[db], 0, 0, 0);
      }
    }
    __builtin_amdgcn_s_setprio(0);

    // ---- publish staged regs into LDS for next tile ----
    __syncthreads();  // everyone done reading Ksh/Vsh
    if (has_next) {
#pragma unroll
      for (int ph = 0; ph < 4; ++ph) {
        *(bf16x8*)&Ksh[ksr[ph] * 128 + ((kcc[ph] ^ (ksr[ph] & 7)) << 3)] = kst[ph];
        *(bf16x8*)&Vsh[vdr[ph] * 64 + ((vcc[ph] ^ (vdr[ph] & 7)) << 3)] = vst[ph];
      }
      __syncthreads();  // writes visible
    }
  }

  // ---- epilogue: finalize l (cross-group), broadcast to acc layout ----
  float lt = l_part + __shfl_xor(l_part, 16, 64);
  lt = lt + __shfl_xor(lt, 32, 64);
  float inv = 1.0f / lt;
  float ij[4];
#pragma unroll
  for (int j = 0; j < 4; ++j) ij[j] = __shfl(inv, (ln & 48) + g * 4 + j, 64);
#pragma unroll
  for (int j = 0; j < 4; ++j) {
    int tt = t0 + g * 4 + j;
    u16* orow = attn + (size_t)tt * HID + h * HD;
#pragma unroll
    for (int db = 0; db < 8; ++db) orow[db * 16 + r16] = f2bf(acc_o[db][j] * ij[j]);
  }
}

extern "C" void kernel_launch(void* const* d_in, const int* in_sizes, int n_in,
                              void* d_out, int out_size, void* d_ws, size_t ws_size,
                              hipStream_t stream) {
  const float* hs   = (const float*)d_in[0];
  const float* cs   = (const float*)d_in[1];
  const float* sn   = (const float*)d_in[2];
  const float* wqkv = (const float*)d_in[3];
  const float* qw   = (const float*)d_in[4];
  const float* kw   = (const float*)d_in[5];
  const float* wo   = (const float*)d_in[6];
  float* out = (float*)d_out;

  u16* ws      = (u16*)d_ws;
  u16* hs_bf   = ws;                       // 6291456 elems
  u16* wqkv_bf = hs_bf + 6291456;          // 6291456
  u16* wo_bf   = wqkv_bf + 6291456;        // 4194304
  u16* qkv     = wo_bf + 4194304;          // 9437184 (V region unused)
  u16* vt      = qkv + 9437184;            // 1572864  (V^T: [4*128][3072])
  u16* attn    = hs_bf;                    // reuse (hs_bf dead after GEMM1)

  k_cvt<<<2048, 256, 0, stream>>>(hs, hs_bf, T_TOK * HID);
  k_cvt<<<2048, 256, 0, stream>>>(wqkv, wqkv_bf, QKVN * HID);
  k_cvt<<<1024, 256, 0, stream>>>(wo, wo_bf, HID * HID);
  // GEMM1: 3072x3072x2048, BM=BN=192 -> 16x16 = 256 blocks (1/CU, no tail)
  k_gemm2p<6, 3, true, true><<<dim3(16, 16), 512, 0, stream>>>(hs_bf, wqkv_bf, qkv, vt,
                                                               T_TOK, QKVN, HID);
  k_normrope<<<dim3(T_TOK, 5), 256, 0, stream>>>(qkv, cs, sn, qw, kw);
  k_attn<<<768, 256, 0, stream>>>(qkv, vt, attn);
  // GEMM2: 3072x2048x2048, BM=192 BN=128 -> 16x16 = 256 blocks
  k_gemm2p<6, 2, false, false><<<dim3(16, 16), 512, 0, stream>>>(attn, wo_bf, out, nullptr,
                                                                 T_TOK, HID, HID);
}

// Round 11
// 156.926 us; speedup vs baseline: 1.3471x; 1.3471x over previous
//
#include <hip/hip_runtime.h>

typedef unsigned short u16;
typedef unsigned int u32;
typedef __attribute__((ext_vector_type(8))) short bf16x8;
typedef __attribute__((ext_vector_type(4))) float f32x4;
typedef __attribute__((ext_vector_type(4))) u32 u32x4;

#define T_TOK 3072
#define HID 2048
#define NH 16
#define NKV 4
#define HD 128
#define QKVN 3072
#define ATT_SCALE 0.08838834764831845f
#define LOG2E 1.4426950408889634f
#define SCL2 (ATT_SCALE * LOG2E)

__device__ __forceinline__ u16 f2bf(float x) {
  u32 u = __builtin_bit_cast(u32, x);
  u = u + 0x7FFFu + ((u >> 16) & 1u);
  return (u16)(u >> 16);
}
__device__ __forceinline__ float bf2f(u16 h) {
  return __builtin_bit_cast(float, (u32)h << 16);
}
__device__ __forceinline__ void gload16(const void* g, void* l) {
  __builtin_amdgcn_global_load_lds((const __attribute__((address_space(1))) void*)g,
                                   (__attribute__((address_space(3))) void*)l, 16, 0, 0);
}

// ---------------- fp32 -> bf16 convert ----------------
__global__ void k_cvt(const float* __restrict__ src, u16* __restrict__ dst, int n) {
  int i = (blockIdx.x * 256 + threadIdx.x) * 4;
  int stride = gridDim.x * 256 * 4;
  for (; i < n; i += stride) {
    float4 v = *(const float4*)(src + i);
    u32 lo = (u32)f2bf(v.x) | ((u32)f2bf(v.y) << 16);
    u32 hi = (u32)f2bf(v.z) | ((u32)f2bf(v.w) << 16);
    *(uint2*)(dst + i) = make_uint2(lo, hi);
  }
}

// ---------------- 2-phase double-buffered GEMM: C = A * B^T ----------------
// (unchanged — matched prediction in round 7)
template <int MR, int NR, bool OUT_BF16, bool VT_MODE>
__global__ __launch_bounds__(512) void k_gemm2p(const u16* __restrict__ A,
                                                const u16* __restrict__ B,
                                                void* __restrict__ Cp,
                                                u16* __restrict__ vt,
                                                int M, int N, int K) {
  constexpr int BM = 32 * MR;
  constexpr int BN = 64 * NR;
  __shared__ u16 Ash[2][BM * 64];
  __shared__ u16 Bsh[2][BN * 64];
  const int tid = threadIdx.x;
  const int wv = tid >> 6, ln = tid & 63;
  const int wr = wv >> 2, wc = wv & 3;
  const int g = ln >> 4, r16 = ln & 15;
  const int m0 = blockIdx.y * BM, n0 = blockIdx.x * BN;
  const int NT = K >> 6;
  const int srow = ln >> 3;                   // row within 8-row DMA block
  const int sswz = ((ln & 7) ^ srow) << 3;    // pre-swizzled source col (elems)
  const u16* Abase = A + (size_t)m0 * K;
  const u16* Bbase = B + (size_t)n0 * K;
  const int xorc = (r16 & 7) << 3;

  f32x4 acc[MR][NR] = {};

  auto stage = [&](int buf, int T) {
#pragma unroll
    for (int a = 0; a < BM / 64; ++a)
      gload16(Abase + (size_t)(a * 64 + wv * 8 + srow) * K + T * 64 + sswz,
              &Ash[buf][(a * 64 + wv * 8) * 64]);
#pragma unroll
    for (int b = 0; b < BN / 64; ++b)
      gload16(Bbase + (size_t)(b * 64 + wv * 8 + srow) * K + T * 64 + sswz,
              &Bsh[buf][(b * 64 + wv * 8) * 64]);
  };

  stage(0, 0);
  __syncthreads();
  int cur = 0;
  for (int T = 0; T < NT; ++T) {
    if (T + 1 < NT) stage(cur ^ 1, T + 1);
    const u16* As = Ash[cur];
    const u16* Bs = Bsh[cur];
#pragma unroll
    for (int kk = 0; kk < 2; ++kk) {
      const int ecol = (kk * 32 + g * 8) ^ xorc;
      bf16x8 af[MR], bfr[NR];
#pragma unroll
      for (int m = 0; m < MR; ++m)
        af[m] = *(const bf16x8*)&As[(wr * (MR * 16) + m * 16 + r16) * 64 + ecol];
#pragma unroll
      for (int n = 0; n < NR; ++n)
        bfr[n] = *(const bf16x8*)&Bs[(wc * (NR * 16) + n * 16 + r16) * 64 + ecol];
      __builtin_amdgcn_s_setprio(1);
#pragma unroll
      for (int m = 0; m < MR; ++m)
#pragma unroll
        for (int n = 0; n < NR; ++n)
          acc[m][n] = __builtin_amdgcn_mfma_f32_16x16x32_bf16(af[m], bfr[n], acc[m][n], 0, 0, 0);
      __builtin_amdgcn_s_setprio(0);
    }
    __syncthreads();
    cur ^= 1;
  }
  // ---- epilogue ----
#pragma unroll
  for (int n = 0; n < NR; ++n) {
    int col = n0 + wc * (NR * 16) + n * 16 + r16;
    bool tov = VT_MODE && (col >= 2560);
#pragma unroll
    for (int m = 0; m < MR; ++m) {
      int row = m0 + wr * (MR * 16) + m * 16 + g * 4;
      if (tov) {
        u32 lo2 = (u32)f2bf(acc[m][n][0]) | ((u32)f2bf(acc[m][n][1]) << 16);
        u32 hi2 = (u32)f2bf(acc[m][n][2]) | ((u32)f2bf(acc[m][n][3]) << 16);
        *(uint2*)&vt[(size_t)(col - 2560) * T_TOK + row] = make_uint2(lo2, hi2);
      } else {
#pragma unroll
        for (int j = 0; j < 4; ++j) {
          if (OUT_BF16)
            ((u16*)Cp)[(size_t)(row + j) * N + col] = f2bf(acc[m][n][j]);
          else
            ((float*)Cp)[(size_t)(row + j) * N + col] = acc[m][n][j];
        }
      }
    }
  }
}

// ---------------- RMSNorm + RoPE (in-place on bf16 qkv, Q and K only) ----------------
__global__ void k_normrope(u16* __restrict__ qkv, const float* __restrict__ cs,
                           const float* __restrict__ sn, const float* __restrict__ qw,
                           const float* __restrict__ kw) {
  int t = blockIdx.x;
  int idx = blockIdx.y * 4 + (threadIdx.x >> 6);  // 0..19
  int l = threadIdx.x & 63;
  bool isq = idx < NH;
  int off = isq ? idx * HD : HID + (idx - NH) * HD;
  u16* p = qkv + (size_t)t * QKVN + off;
  float x0 = bf2f(p[l]), x1 = bf2f(p[l + 64]);
  float ss = x0 * x0 + x1 * x1;
#pragma unroll
  for (int d = 1; d < 64; d <<= 1) ss += __shfl_xor(ss, d, 64);
  float rs = rsqrtf(ss * (1.0f / 128.0f) + 1e-6f);
  const float* w = isq ? qw : kw;
  float xn0 = x0 * rs * w[l];
  float xn1 = x1 * rs * w[l + 64];
  const float* ct = cs + (size_t)t * HD;
  const float* st = sn + (size_t)t * HD;
  float o0 = xn0 * ct[l] - xn1 * st[l];
  float o1 = xn1 * ct[l + 64] + xn0 * st[l + 64];
  p[l] = f2bf(o0);
  p[l + 64] = f2bf(o1);
}

// ---------------- GQA attention: swapped-QK in-reg softmax, DMA-staged LDS ----------------
// Validated round-10 math (swapped mfma(K,Q), shfl P-rearrange, defer-max,
// mask specialization) with the spill removed: no T14 regs, staging via
// global_load_lds with pre-swizzled source (rule-21), linear LDS dest,
// swizzled ds_read. LDS 32KB -> 4 blocks/CU.
__global__ __launch_bounds__(256, 4) void k_attn(const u16* __restrict__ qkv,
                                                 const u16* __restrict__ vt,
                                                 u16* __restrict__ attn) {
  __shared__ u16 Ksh[64 * 128];     // [s][granule ^ (s&7)]
  __shared__ u16 Vsh[128 * 64];     // [d][granule ^ (d&7)]
  const int id = blockIdx.x;
  const int xcd = id & 7, slot = id >> 3;              // slot 0..95
  const int hkv = xcd >> 1;                            // 2 XCDs per kv-group
  const int t0 = (191 - (slot * 2 + (xcd & 1))) * 16;  // reversed: long blocks first
  const int tid = threadIdx.x, wv = tid >> 6, ln = tid & 63;
  const int g = ln >> 4, r16 = ln & 15;
  const int h = hkv * 4 + wv;
  const int swz = r16 & 7;
  const bool ghi = (g >> 1) != 0;
  const int L0 = r16 + 16 * ((2 * g) & 3);   // src lanes for P-fragment shfl
  const int L1 = r16 + 16 * ((2 * g + 1) & 3);

  bf16x8 qf[4];
  const u16* qrow = qkv + (size_t)(t0 + r16) * QKVN + h * HD;
#pragma unroll
  for (int kk = 0; kk < 4; ++kk) qf[kk] = *(const bf16x8*)(qrow + kk * 32 + g * 8);

  float m_run = -1e30f, l_part = 0.f;   // row t = t0 + r16 (per-lane)
  f32x4 acc_o[8] = {};                  // rows t = t0 + g*4+j, cols d = db*16+r16

  const u16* Kbase = qkv + HID + hkv * HD;
  const u16* Vbase = vt + (size_t)(hkv * HD) * T_TOK;

  int lo = t0 - 1023;
  if (lo < 0) lo = 0;
  lo &= ~63;
  const int t_hi = t0 + 15;

  for (int s0 = lo; s0 <= t_hi; s0 += 64) {
    // ---- stage K [64][128] + V^T [128][64] via global_load_lds ----
    // K: wave wv rows [wv*16, wv*16+16), 4 rows per DMA; lane ln -> row
    // ks=base+(ln>>4), slot ln&15, source granule (ln&15)^(ks&7).
#pragma unroll
    for (int ph = 0; ph < 4; ++ph) {
      int ks = wv * 16 + ph * 4 + (ln >> 4);
      int kc = (ln & 15) ^ (ks & 7);
      gload16(Kbase + (size_t)(s0 + ks) * QKVN + (kc << 3),
              &Ksh[(wv * 16 + ph * 4) * 128]);
      int vd = wv * 32 + ph * 8 + (ln >> 3);
      int vc = (ln & 7) ^ (vd & 7);
      gload16(Vbase + (size_t)vd * T_TOK + s0 + (vc << 3),
              &Vsh[(wv * 32 + ph * 8) * 64]);
    }
    __syncthreads();  // drains vmcnt(0): staged data visible

    // ---- S^T = K Q^T (swapped): sc[sb] rows s_local=g*4+j, cols t=r16 ----
    f32x4 sc[4] = {};
    __builtin_amdgcn_s_setprio(1);
#pragma unroll
    for (int sb = 0; sb < 4; ++sb) {
#pragma unroll
      for (int kk = 0; kk < 4; ++kk) {
        const bf16x8 kf =
            *(const bf16x8*)&Ksh[(sb * 16 + r16) * 128 + (((kk * 4 + g) ^ swz) << 3)];
        sc[sb] = __builtin_amdgcn_mfma_f32_16x16x32_bf16(kf, qf[kk], sc[sb], 0, 0, 0);
      }
    }
    __builtin_amdgcn_s_setprio(0);

    // ---- mask (specialized: only last tile + window tile) + row max ----
    const bool mtile = (s0 > t0 - 60) || (t0 >= 1024 && s0 == lo);
    const int t = t0 + r16;
    float pmax = -__builtin_inff();
    if (mtile) {
#pragma unroll
      for (int sb = 0; sb < 4; ++sb)
#pragma unroll
        for (int j = 0; j < 4; ++j) {
          int s = s0 + sb * 16 + g * 4 + j;
          bool ok = (s <= (t | 3)) && (t - s < 1024);
          float x = ok ? sc[sb][j] : -__builtin_inff();
          sc[sb][j] = x;
          pmax = fmaxf(pmax, x);
        }
    } else {
#pragma unroll
      for (int sb = 0; sb < 4; ++sb)
#pragma unroll
        for (int j = 0; j < 4; ++j) pmax = fmaxf(pmax, sc[sb][j]);
    }
    pmax = fmaxf(pmax, __shfl_xor(pmax, 16, 64));
    pmax = fmaxf(pmax, __shfl_xor(pmax, 32, 64));

    // ---- defer-max online softmax (log2 domain) ----
    float needv = fmaf(pmax, SCL2, -m_run);
    if (!__all(needv <= 11.5f)) {
      float mnew = fmaxf(m_run, pmax * SCL2);
      float fac = exp2f(m_run - mnew);
      m_run = mnew;
      l_part *= fac;
      float fj[4];
#pragma unroll
      for (int j = 0; j < 4; ++j) fj[j] = __shfl(fac, (ln & 48) + g * 4 + j, 64);
#pragma unroll
      for (int db = 0; db < 8; ++db)
#pragma unroll
        for (int j = 0; j < 4; ++j) acc_o[db][j] *= fj[j];
    }
    const float nm = -m_run;
    u32 w0[4], w1[4];
#pragma unroll
    for (int sb = 0; sb < 4; ++sb) {
      float e0 = exp2f(fmaf(sc[sb][0], SCL2, nm));
      float e1 = exp2f(fmaf(sc[sb][1], SCL2, nm));
      float e2 = exp2f(fmaf(sc[sb][2], SCL2, nm));
      float e3 = exp2f(fmaf(sc[sb][3], SCL2, nm));
      l_part += (e0 + e1) + (e2 + e3);
      w0[sb] = (u32)f2bf(e0) | ((u32)f2bf(e1) << 16);
      w1[sb] = (u32)f2bf(e2) | ((u32)f2bf(e3) << 16);
    }

    // ---- O += P V: P rearranged lane->A-fragment via shfl (no LDS) ----
    __builtin_amdgcn_s_setprio(1);
#pragma unroll
    for (int s32 = 0; s32 < 2; ++s32) {
      u32 a0 = __shfl(w0[2 * s32], L0, 64), b0 = __shfl(w0[2 * s32 + 1], L0, 64);
      u32 a1 = __shfl(w1[2 * s32], L0, 64), b1 = __shfl(w1[2 * s32 + 1], L0, 64);
      u32 a2 = __shfl(w0[2 * s32], L1, 64), b2 = __shfl(w0[2 * s32 + 1], L1, 64);
      u32 a3 = __shfl(w1[2 * s32], L1, 64), b3 = __shfl(w1[2 * s32 + 1], L1, 64);
      u32x4 pw;
      pw[0] = ghi ? b0 : a0;
      pw[1] = ghi ? b1 : a1;
      pw[2] = ghi ? b2 : a2;
      pw[3] = ghi ? b3 : a3;
      const bf16x8 pa = __builtin_bit_cast(bf16x8, pw);
#pragma unroll
      for (int db = 0; db < 8; ++db) {
        const bf16x8 vb =
            *(const bf16x8*)&Vsh[(db * 16 + r16) * 64 + (((s32 * 4 + g) ^ swz) << 3)];
        acc_o[db] = __builtin_amdgcn_mfma_f32_16x16x32_bf16(pa, vb, acc_o[db], 0, 0, 0);
      }
    }
    __builtin_amdgcn_s_setprio(0);
    __syncthreads();  // all waves done reading before next tile's DMA lands
  }

  // ---- epilogue: finalize l (cross-group), broadcast to acc layout ----
  float lt = l_part + __shfl_xor(l_part, 16, 64);
  lt = lt + __shfl_xor(lt, 32, 64);
  float inv = 1.0f / lt;
  float ij[4];
#pragma unroll
  for (int j = 0; j < 4; ++j) ij[j] = __shfl(inv, (ln & 48) + g * 4 + j, 64);
#pragma unroll
  for (int j = 0; j < 4; ++j) {
    int tt = t0 + g * 4 + j;
    u16* orow = attn + (size_t)tt * HID + h * HD;
#pragma unroll
    for (int db = 0; db < 8; ++db) orow[db * 16 + r16] = f2bf(acc_o[db][j] * ij[j]);
  }
}

extern "C" void kernel_launch(void* const* d_in, const int* in_sizes, int n_in,
                              void* d_out, int out_size, void* d_ws, size_t ws_size,
                              hipStream_t stream) {
  const float* hs   = (const float*)d_in[0];
  const float* cs   = (const float*)d_in[1];
  const float* sn   = (const float*)d_in[2];
  const float* wqkv = (const float*)d_in[3];
  const float* qw   = (const float*)d_in[4];
  const float* kw   = (const float*)d_in[5];
  const float* wo   = (const float*)d_in[6];
  float* out = (float*)d_out;

  u16* ws      = (u16*)d_ws;
  u16* hs_bf   = ws;                       // 6291456 elems
  u16* wqkv_bf = hs_bf + 6291456;          // 6291456
  u16* wo_bf   = wqkv_bf + 6291456;        // 4194304
  u16* qkv     = wo_bf + 4194304;          // 9437184 (V region unused)
  u16* vt      = qkv + 9437184;            // 1572864  (V^T: [4*128][3072])
  u16* attn    = hs_bf;                    // reuse (hs_bf dead after GEMM1)

  k_cvt<<<2048, 256, 0, stream>>>(hs, hs_bf, T_TOK * HID);
  k_cvt<<<2048, 256, 0, stream>>>(wqkv, wqkv_bf, QKVN * HID);
  k_cvt<<<1024, 256, 0, stream>>>(wo, wo_bf, HID * HID);
  // GEMM1: 3072x3072x2048, BM=BN=192 -> 16x16 = 256 blocks (1/CU, no tail)
  k_gemm2p<6, 3, true, true><<<dim3(16, 16), 512, 0, stream>>>(hs_bf, wqkv_bf, qkv, vt,
                                                               T_TOK, QKVN, HID);
  k_normrope<<<dim3(T_TOK, 5), 256, 0, stream>>>(qkv, cs, sn, qw, kw);
  k_attn<<<768, 256, 0, stream>>>(qkv, vt, attn);
  // GEMM2: 3072x2048x2048, BM=192 BN=128 -> 16x16 = 256 blocks
  k_gemm2p<6, 2, false, false><<<dim3(16, 16), 512, 0, stream>>>(attn, wo_bf, out, nullptr,
                                                                 T_TOK, HID, HID);
}

// Round 12
// 153.691 us; speedup vs baseline: 1.3754x; 1.0210x over previous
//
#include <hip/hip_runtime.h>

typedef unsigned short u16;
typedef unsigned int u32;
typedef __attribute__((ext_vector_type(8))) short bf16x8;
typedef __attribute__((ext_vector_type(4))) float f32x4;
typedef __attribute__((ext_vector_type(4))) u32 u32x4;

#define T_TOK 3072
#define HID 2048
#define NH 16
#define NKV 4
#define HD 128
#define QKVN 3072
#define ATT_SCALE 0.08838834764831845f
#define LOG2E 1.4426950408889634f
#define SCL2 (ATT_SCALE * LOG2E)

__device__ __forceinline__ u16 f2bf(float x) {
  u32 u = __builtin_bit_cast(u32, x);
  u = u + 0x7FFFu + ((u >> 16) & 1u);
  return (u16)(u >> 16);
}
__device__ __forceinline__ float bf2f(u16 h) {
  return __builtin_bit_cast(float, (u32)h << 16);
}
__device__ __forceinline__ u32 cvtpk(float lo, float hi) {
  u32 r;
  asm("v_cvt_pk_bf16_f32 %0, %1, %2" : "=v"(r) : "v"(lo), "v"(hi));
  return r;
}
__device__ __forceinline__ void gload16(const void* g, void* l) {
  __builtin_amdgcn_global_load_lds((const __attribute__((address_space(1))) void*)g,
                                   (__attribute__((address_space(3))) void*)l, 16, 0, 0);
}

// ---------------- fp32 -> bf16 convert, 3 regions in one launch ----------------
__global__ void k_cvt3(const float* __restrict__ s0p, u16* __restrict__ d0p, int n0,
                       const float* __restrict__ s1p, u16* __restrict__ d1p, int n1,
                       const float* __restrict__ s2p, u16* __restrict__ d2p, int n2) {
  const float* s;
  u16* d;
  int n, b = blockIdx.x, nb;
  if (b < 1024) {
    s = s0p; d = d0p; n = n0; nb = 1024;
  } else if (b < 2048) {
    s = s1p; d = d1p; n = n1; b -= 1024; nb = 1024;
  } else {
    s = s2p; d = d2p; n = n2; b -= 2048; nb = 512;
  }
  int i = (b * 256 + threadIdx.x) * 4;
  int stride = nb * 256 * 4;
  for (; i < n; i += stride) {
    float4 v = *(const float4*)(s + i);
    u32 lo = cvtpk(v.x, v.y);
    u32 hi = cvtpk(v.z, v.w);
    *(uint2*)(d + i) = make_uint2(lo, hi);
  }
}

// ---------------- 2-phase double-buffered GEMM: C = A * B^T ----------------
// (unchanged — matched prediction in round 7)
template <int MR, int NR, bool OUT_BF16, bool VT_MODE>
__global__ __launch_bounds__(512) void k_gemm2p(const u16* __restrict__ A,
                                                const u16* __restrict__ B,
                                                void* __restrict__ Cp,
                                                u16* __restrict__ vt,
                                                int M, int N, int K) {
  constexpr int BM = 32 * MR;
  constexpr int BN = 64 * NR;
  __shared__ u16 Ash[2][BM * 64];
  __shared__ u16 Bsh[2][BN * 64];
  const int tid = threadIdx.x;
  const int wv = tid >> 6, ln = tid & 63;
  const int wr = wv >> 2, wc = wv & 3;
  const int g = ln >> 4, r16 = ln & 15;
  const int m0 = blockIdx.y * BM, n0 = blockIdx.x * BN;
  const int NT = K >> 6;
  const int srow = ln >> 3;                   // row within 8-row DMA block
  const int sswz = ((ln & 7) ^ srow) << 3;    // pre-swizzled source col (elems)
  const u16* Abase = A + (size_t)m0 * K;
  const u16* Bbase = B + (size_t)n0 * K;
  const int xorc = (r16 & 7) << 3;

  f32x4 acc[MR][NR] = {};

  auto stage = [&](int buf, int T) {
#pragma unroll
    for (int a = 0; a < BM / 64; ++a)
      gload16(Abase + (size_t)(a * 64 + wv * 8 + srow) * K + T * 64 + sswz,
              &Ash[buf][(a * 64 + wv * 8) * 64]);
#pragma unroll
    for (int b = 0; b < BN / 64; ++b)
      gload16(Bbase + (size_t)(b * 64 + wv * 8 + srow) * K + T * 64 + sswz,
              &Bsh[buf][(b * 64 + wv * 8) * 64]);
  };

  stage(0, 0);
  __syncthreads();
  int cur = 0;
  for (int T = 0; T < NT; ++T) {
    if (T + 1 < NT) stage(cur ^ 1, T + 1);
    const u16* As = Ash[cur];
    const u16* Bs = Bsh[cur];
#pragma unroll
    for (int kk = 0; kk < 2; ++kk) {
      const int ecol = (kk * 32 + g * 8) ^ xorc;
      bf16x8 af[MR], bfr[NR];
#pragma unroll
      for (int m = 0; m < MR; ++m)
        af[m] = *(const bf16x8*)&As[(wr * (MR * 16) + m * 16 + r16) * 64 + ecol];
#pragma unroll
      for (int n = 0; n < NR; ++n)
        bfr[n] = *(const bf16x8*)&Bs[(wc * (NR * 16) + n * 16 + r16) * 64 + ecol];
      __builtin_amdgcn_s_setprio(1);
#pragma unroll
      for (int m = 0; m < MR; ++m)
#pragma unroll
        for (int n = 0; n < NR; ++n)
          acc[m][n] = __builtin_amdgcn_mfma_f32_16x16x32_bf16(af[m], bfr[n], acc[m][n], 0, 0, 0);
      __builtin_amdgcn_s_setprio(0);
    }
    __syncthreads();
    cur ^= 1;
  }
  // ---- epilogue ----
#pragma unroll
  for (int n = 0; n < NR; ++n) {
    int col = n0 + wc * (NR * 16) + n * 16 + r16;
    bool tov = VT_MODE && (col >= 2560);
#pragma unroll
    for (int m = 0; m < MR; ++m) {
      int row = m0 + wr * (MR * 16) + m * 16 + g * 4;
      if (tov) {
        u32 lo2 = (u32)f2bf(acc[m][n][0]) | ((u32)f2bf(acc[m][n][1]) << 16);
        u32 hi2 = (u32)f2bf(acc[m][n][2]) | ((u32)f2bf(acc[m][n][3]) << 16);
        *(uint2*)&vt[(size_t)(col - 2560) * T_TOK + row] = make_uint2(lo2, hi2);
      } else {
#pragma unroll
        for (int j = 0; j < 4; ++j) {
          if (OUT_BF16)
            ((u16*)Cp)[(size_t)(row + j) * N + col] = f2bf(acc[m][n][j]);
          else
            ((float*)Cp)[(size_t)(row + j) * N + col] = acc[m][n][j];
        }
      }
    }
  }
}

// ---------------- RMSNorm + RoPE (in-place on bf16 qkv, Q and K only) ----------------
__global__ void k_normrope(u16* __restrict__ qkv, const float* __restrict__ cs,
                           const float* __restrict__ sn, const float* __restrict__ qw,
                           const float* __restrict__ kw) {
  int t = blockIdx.x;
  int idx = blockIdx.y * 4 + (threadIdx.x >> 6);  // 0..19
  int l = threadIdx.x & 63;
  bool isq = idx < NH;
  int off = isq ? idx * HD : HID + (idx - NH) * HD;
  u16* p = qkv + (size_t)t * QKVN + off;
  float x0 = bf2f(p[l]), x1 = bf2f(p[l + 64]);
  float ss = x0 * x0 + x1 * x1;
#pragma unroll
  for (int d = 1; d < 64; d <<= 1) ss += __shfl_xor(ss, d, 64);
  float rs = rsqrtf(ss * (1.0f / 128.0f) + 1e-6f);
  const float* w = isq ? qw : kw;
  float xn0 = x0 * rs * w[l];
  float xn1 = x1 * rs * w[l + 64];
  const float* ct = cs + (size_t)t * HD;
  const float* st = sn + (size_t)t * HD;
  float o0 = xn0 * ct[l] - xn1 * st[l];
  float o1 = xn1 * ct[l + 64] + xn0 * st[l + 64];
  p[l] = f2bf(o0);
  p[l + 64] = f2bf(o1);
}

// ---------------- GQA attention: swapped-QK in-reg softmax, DMA-staged LDS ----------------
// Round-11 structure + v_cvt_pk_bf16_f32 for the P->bf16 pack (T12):
// 8 cvt_pk insts replace ~72 VALU ops/tile (f2bf x16 + packs).
__global__ __launch_bounds__(256, 4) void k_attn(const u16* __restrict__ qkv,
                                                 const u16* __restrict__ vt,
                                                 u16* __restrict__ attn) {
  __shared__ u16 Ksh[64 * 128];     // [s][granule ^ (s&7)]
  __shared__ u16 Vsh[128 * 64];     // [d][granule ^ (d&7)]
  const int id = blockIdx.x;
  const int xcd = id & 7, slot = id >> 3;              // slot 0..95
  const int hkv = xcd >> 1;                            // 2 XCDs per kv-group
  const int t0 = (191 - (slot * 2 + (xcd & 1))) * 16;  // reversed: long blocks first
  const int tid = threadIdx.x, wv = tid >> 6, ln = tid & 63;
  const int g = ln >> 4, r16 = ln & 15;
  const int h = hkv * 4 + wv;
  const int swz = r16 & 7;
  const bool ghi = (g >> 1) != 0;
  const int L0 = r16 + 16 * ((2 * g) & 3);   // src lanes for P-fragment shfl
  const int L1 = r16 + 16 * ((2 * g + 1) & 3);

  bf16x8 qf[4];
  const u16* qrow = qkv + (size_t)(t0 + r16) * QKVN + h * HD;
#pragma unroll
  for (int kk = 0; kk < 4; ++kk) qf[kk] = *(const bf16x8*)(qrow + kk * 32 + g * 8);

  float m_run = -1e30f, l_part = 0.f;   // row t = t0 + r16 (per-lane)
  f32x4 acc_o[8] = {};                  // rows t = t0 + g*4+j, cols d = db*16+r16

  const u16* Kbase = qkv + HID + hkv * HD;
  const u16* Vbase = vt + (size_t)(hkv * HD) * T_TOK;

  int lo = t0 - 1023;
  if (lo < 0) lo = 0;
  lo &= ~63;
  const int t_hi = t0 + 15;

  for (int s0 = lo; s0 <= t_hi; s0 += 64) {
    // ---- stage K [64][128] + V^T [128][64] via global_load_lds ----
#pragma unroll
    for (int ph = 0; ph < 4; ++ph) {
      int ks = wv * 16 + ph * 4 + (ln >> 4);
      int kc = (ln & 15) ^ (ks & 7);
      gload16(Kbase + (size_t)(s0 + ks) * QKVN + (kc << 3),
              &Ksh[(wv * 16 + ph * 4) * 128]);
      int vd = wv * 32 + ph * 8 + (ln >> 3);
      int vc = (ln & 7) ^ (vd & 7);
      gload16(Vbase + (size_t)vd * T_TOK + s0 + (vc << 3),
              &Vsh[(wv * 32 + ph * 8) * 64]);
    }
    __syncthreads();  // drains vmcnt(0): staged data visible

    // ---- S^T = K Q^T (swapped): sc[sb] rows s_local=g*4+j, cols t=r16 ----
    f32x4 sc[4] = {};
    __builtin_amdgcn_s_setprio(1);
#pragma unroll
    for (int sb = 0; sb < 4; ++sb) {
#pragma unroll
      for (int kk = 0; kk < 4; ++kk) {
        const bf16x8 kf =
            *(const bf16x8*)&Ksh[(sb * 16 + r16) * 128 + (((kk * 4 + g) ^ swz) << 3)];
        sc[sb] = __builtin_amdgcn_mfma_f32_16x16x32_bf16(kf, qf[kk], sc[sb], 0, 0, 0);
      }
    }
    __builtin_amdgcn_s_setprio(0);

    // ---- mask (specialized: only last tile + window tile) + row max ----
    const bool mtile = (s0 > t0 - 60) || (t0 >= 1024 && s0 == lo);
    const int t = t0 + r16;
    float pmax = -__builtin_inff();
    if (mtile) {
#pragma unroll
      for (int sb = 0; sb < 4; ++sb)
#pragma unroll
        for (int j = 0; j < 4; ++j) {
          int s = s0 + sb * 16 + g * 4 + j;
          bool ok = (s <= (t | 3)) && (t - s < 1024);
          float x = ok ? sc[sb][j] : -__builtin_inff();
          sc[sb][j] = x;
          pmax = fmaxf(pmax, x);
        }
    } else {
#pragma unroll
      for (int sb = 0; sb < 4; ++sb)
#pragma unroll
        for (int j = 0; j < 4; ++j) pmax = fmaxf(pmax, sc[sb][j]);
    }
    pmax = fmaxf(pmax, __shfl_xor(pmax, 16, 64));
    pmax = fmaxf(pmax, __shfl_xor(pmax, 32, 64));

    // ---- defer-max online softmax (log2 domain) ----
    float needv = fmaf(pmax, SCL2, -m_run);
    if (!__all(needv <= 11.5f)) {
      float mnew = fmaxf(m_run, pmax * SCL2);
      float fac = exp2f(m_run - mnew);
      m_run = mnew;
      l_part *= fac;
      float fj[4];
#pragma unroll
      for (int j = 0; j < 4; ++j) fj[j] = __shfl(fac, (ln & 48) + g * 4 + j, 64);
#pragma unroll
      for (int db = 0; db < 8; ++db)
#pragma unroll
        for (int j = 0; j < 4; ++j) acc_o[db][j] *= fj[j];
    }
    const float nm = -m_run;
    u32 w0[4], w1[4];
#pragma unroll
    for (int sb = 0; sb < 4; ++sb) {
      float e0 = exp2f(fmaf(sc[sb][0], SCL2, nm));
      float e1 = exp2f(fmaf(sc[sb][1], SCL2, nm));
      float e2 = exp2f(fmaf(sc[sb][2], SCL2, nm));
      float e3 = exp2f(fmaf(sc[sb][3], SCL2, nm));
      l_part += (e0 + e1) + (e2 + e3);
      w0[sb] = cvtpk(e0, e1);
      w1[sb] = cvtpk(e2, e3);
    }

    // ---- O += P V: P rearranged lane->A-fragment via shfl (no LDS) ----
    __builtin_amdgcn_s_setprio(1);
#pragma unroll
    for (int s32 = 0; s32 < 2; ++s32) {
      u32 a0 = __shfl(w0[2 * s32], L0, 64), b0 = __shfl(w0[2 * s32 + 1], L0, 64);
      u32 a1 = __shfl(w1[2 * s32], L0, 64), b1 = __shfl(w1[2 * s32 + 1], L0, 64);
      u32 a2 = __shfl(w0[2 * s32], L1, 64), b2 = __shfl(w0[2 * s32 + 1], L1, 64);
      u32 a3 = __shfl(w1[2 * s32], L1, 64), b3 = __shfl(w1[2 * s32 + 1], L1, 64);
      u32x4 pw;
      pw[0] = ghi ? b0 : a0;
      pw[1] = ghi ? b1 : a1;
      pw[2] = ghi ? b2 : a2;
      pw[3] = ghi ? b3 : a3;
      const bf16x8 pa = __builtin_bit_cast(bf16x8, pw);
#pragma unroll
      for (int db = 0; db < 8; ++db) {
        const bf16x8 vb =
            *(const bf16x8*)&Vsh[(db * 16 + r16) * 64 + (((s32 * 4 + g) ^ swz) << 3)];
        acc_o[db] = __builtin_amdgcn_mfma_f32_16x16x32_bf16(pa, vb, acc_o[db], 0, 0, 0);
      }
    }
    __builtin_amdgcn_s_setprio(0);
    __syncthreads();  // all waves done reading before next tile's DMA lands
  }

  // ---- epilogue: finalize l (cross-group), broadcast to acc layout ----
  float lt = l_part + __shfl_xor(l_part, 16, 64);
  lt = lt + __shfl_xor(lt, 32, 64);
  float inv = 1.0f / lt;
  float ij[4];
#pragma unroll
  for (int j = 0; j < 4; ++j) ij[j] = __shfl(inv, (ln & 48) + g * 4 + j, 64);
#pragma unroll
  for (int j = 0; j < 4; ++j) {
    int tt = t0 + g * 4 + j;
    u16* orow = attn + (size_t)tt * HID + h * HD;
#pragma unroll
    for (int db = 0; db < 8; ++db) orow[db * 16 + r16] = f2bf(acc_o[db][j] * ij[j]);
  }
}

extern "C" void kernel_launch(void* const* d_in, const int* in_sizes, int n_in,
                              void* d_out, int out_size, void* d_ws, size_t ws_size,
                              hipStream_t stream) {
  const float* hs   = (const float*)d_in[0];
  const float* cs   = (const float*)d_in[1];
  const float* sn   = (const float*)d_in[2];
  const float* wqkv = (const float*)d_in[3];
  const float* qw   = (const float*)d_in[4];
  const float* kw   = (const float*)d_in[5];
  const float* wo   = (const float*)d_in[6];
  float* out = (float*)d_out;

  u16* ws      = (u16*)d_ws;
  u16* hs_bf   = ws;                       // 6291456 elems
  u16* wqkv_bf = hs_bf + 6291456;          // 6291456
  u16* wo_bf   = wqkv_bf + 6291456;        // 4194304
  u16* qkv     = wo_bf + 4194304;          // 9437184 (V region unused)
  u16* vt      = qkv + 9437184;            // 1572864  (V^T: [4*128][3072])
  u16* attn    = hs_bf;                    // reuse (hs_bf dead after GEMM1)

  k_cvt3<<<2560, 256, 0, stream>>>(hs, hs_bf, T_TOK * HID,
                                   wqkv, wqkv_bf, QKVN * HID,
                                   wo, wo_bf, HID * HID);
  // GEMM1: 3072x3072x2048, BM=BN=192 -> 16x16 = 256 blocks (1/CU, no tail)
  k_gemm2p<6, 3, true, true><<<dim3(16, 16), 512, 0, stream>>>(hs_bf, wqkv_bf, qkv, vt,
                                                               T_TOK, QKVN, HID);
  k_normrope<<<dim3(T_TOK, 5), 256, 0, stream>>>(qkv, cs, sn, qw, kw);
  k_attn<<<768, 256, 0, stream>>>(qkv, vt, attn);
  // GEMM2: 3072x2048x2048, BM=192 BN=128 -> 16x16 = 256 blocks
  k_gemm2p<6, 2, false, false><<<dim3(16, 16), 512, 0, stream>>>(attn, wo_bf, out, nullptr,
                                                                 T_TOK, HID, HID);
}